// Round 5
// baseline (197.353 us; speedup 1.0000x reference)
//
#include <hip/hip_runtime.h>
#include <math.h>

namespace {

typedef _Float16 half8 __attribute__((ext_vector_type(8)));
typedef float floatx4 __attribute__((ext_vector_type(4)));

constexpr int kS   = 1024;
constexpr int kD   = 64;
constexpr int kPad = 72;   // 144 B row stride: 16B-aligned, 2-way bank phase (free)
constexpr float kLog2e = 1.4426950408889634f;
constexpr float kThr   = 8.0f;  // defer-rescale threshold (log2 space): p <= 2^8

union H4 { _Float16 h[4]; uint2 u2; };

__device__ __forceinline__ float fast_exp2(float x) {
#if __has_builtin(__builtin_amdgcn_exp2f)
  return __builtin_amdgcn_exp2f(x);
#else
  return exp2f(x);
#endif
}

__device__ __forceinline__ float fast_rcp(float x) {
#if __has_builtin(__builtin_amdgcn_rcpf)
  return __builtin_amdgcn_rcpf(x);
#else
  return 1.0f / x;
#endif
}

// Work is 2048 waves total = 8 waves/CU: occupancy is WORK-limited at 25%.
// So this round attacks per-wave stalls instead: K/V LDS double-buffer
// (1 barrier/tile, staging overlaps compute) + pipelined pass order
// QK0->SM0->QK1->PV0->SM1->PV1 so SM1's VALU co-issues with PV0's MFMA.
__global__ __launch_bounds__(256, 2)
void fa_mfma_kernel(const float* __restrict__ qg, const float* __restrict__ kg,
                    const float* __restrict__ vg, float* __restrict__ og) {
  __shared__ __align__(16) _Float16 sK [2][64][kPad];  // K tiles [buf][key][d]
  __shared__ __align__(16) _Float16 sVt[2][64][kPad];  // V^T tiles [buf][d][key]
  __shared__ __align__(16) _Float16 sP [256][kPad];    // P [qrow(block)][key]

  const int tid  = threadIdx.x;
  const int lane = tid & 63;
  const int w    = __builtin_amdgcn_readfirstlane(tid >> 6);
  const int quad = lane >> 4;
  const int r    = lane & 15;

  // XCD swizzle for 512 blocks: batch b's 4 q-tile blocks -> same XCD (i%8).
  const int blk = blockIdx.x;
  const int b     = (blk & 7) + 8 * (blk >> 5);  // batch 0..127
  const int qbase = ((blk >> 3) & 3) * 256;      // q-tile 0..3 (256 rows each)

  const float* qb = qg + (size_t)b * kS * kD;
  const float* kb = kg + (size_t)b * kS * kD;
  const float* vb = vg + (size_t)b * kS * kD;
  float*       ob = og + (size_t)b * kS * kD;

  // ---- Q fragments direct from global: hi/lo f16 split, pre-scaled log2e ----
  half8 fqh[4][2], fql[4][2];  // [ntq][ks]
#pragma unroll
  for (int ntq = 0; ntq < 4; ++ntq)
#pragma unroll
    for (int ks = 0; ks < 2; ++ks) {
      const float* src =
          qb + (size_t)(qbase + w * 64 + ntq * 16 + r) * kD + ks * 32 + quad * 8;
      float4 a = ((const float4*)src)[0];
      float4 c = ((const float4*)src)[1];
      float f[8] = {a.x, a.y, a.z, a.w, c.x, c.y, c.z, c.w};
#pragma unroll
      for (int j = 0; j < 8; ++j) {
        float x = f[j] * kLog2e;
        _Float16 h = (_Float16)x;
        fqh[ntq][ks][j] = h;
        fql[ntq][ks][j] = (_Float16)(x - (float)h);
      }
    }

  float m_i[4] = {-INFINITY, -INFINITY, -INFINITY, -INFINITY};
  float l_i[4] = {0.f, 0.f, 0.f, 0.f};
  floatx4 O[4][4];
#pragma unroll
  for (int a = 0; a < 4; ++a)
#pragma unroll
    for (int c = 0; c < 4; ++c) O[a][c] = floatx4{0.f, 0.f, 0.f, 0.f};

  // K/V prefetch registers (one tile ahead of the LDS buffer being staged).
  const int krow = tid >> 2, kc0 = (tid & 3) * 16;   // K row-major copy
  const int vkey4 = (tid & 15) * 4;                  // V: 4 consecutive keys
  const int vd0   = (tid >> 4) * 4;                  //    x 4 dims sub-tile
  float4 kbuf[4], vbuf[4];

  auto load_kv = [&](int kt) {
    const float4* ksrc = (const float4*)(kb + (size_t)(kt * 64 + krow) * kD + kc0);
#pragma unroll
    for (int g = 0; g < 4; ++g) kbuf[g] = ksrc[g];
#pragma unroll
    for (int kk = 0; kk < 4; ++kk)
      vbuf[kk] = *(const float4*)(vb + (size_t)(kt * 64 + vkey4 + kk) * kD + vd0);
  };
  auto stage = [&](int bi) {
#pragma unroll
    for (int g = 0; g < 4; ++g) {
      float t[4] = {kbuf[g].x, kbuf[g].y, kbuf[g].z, kbuf[g].w};
      H4 hk;
#pragma unroll
      for (int j = 0; j < 4; ++j) hk.h[j] = (_Float16)t[j];
      *(uint2*)&sK[bi][krow][kc0 + g * 4] = hk.u2;
    }
    float tv[4][4];
#pragma unroll
    for (int kk = 0; kk < 4; ++kk) {
      tv[kk][0] = vbuf[kk].x; tv[kk][1] = vbuf[kk].y;
      tv[kk][2] = vbuf[kk].z; tv[kk][3] = vbuf[kk].w;
    }
#pragma unroll
    for (int j = 0; j < 4; ++j) {
      H4 hv;
#pragma unroll
      for (int kk = 0; kk < 4; ++kk) hv.h[kk] = (_Float16)tv[kk][j];
      *(uint2*)&sVt[bi][vd0 + j][vkey4] = hv.u2;
    }
  };

  // Prologue: buf[0] <- tile 0; regs <- tile 1.
  load_kv(0);
  stage(0);
  load_kv(1);

  for (int kt = 0; kt < kS / 64; ++kt) {
    const int cur = kt & 1, nxt = cur ^ 1;
    __syncthreads();  // buf[cur] staged & prior reads of buf[nxt] done
    stage(nxt);                // tile kt+1 -> other buffer (overlaps compute)
    load_kv((kt + 2) & 15);    // regs <- tile kt+2 (wrap harmless)

    // ---- QK pass 0 (q-groups 0,1) ----
    floatx4 S0[2][4];
    __builtin_amdgcn_s_setprio(1);
#pragma unroll
    for (int mt = 0; mt < 4; ++mt) {
      half8 fk0 = *(const half8*)&sK[cur][mt * 16 + r][quad * 8];
      half8 fk1 = *(const half8*)&sK[cur][mt * 16 + r][32 + quad * 8];
#pragma unroll
      for (int g = 0; g < 2; ++g) {
        floatx4 ah = {0.f, 0.f, 0.f, 0.f}, al = {0.f, 0.f, 0.f, 0.f};
        ah = __builtin_amdgcn_mfma_f32_16x16x32_f16(fk0, fqh[g][0], ah, 0, 0, 0);
        ah = __builtin_amdgcn_mfma_f32_16x16x32_f16(fk1, fqh[g][1], ah, 0, 0, 0);
        al = __builtin_amdgcn_mfma_f32_16x16x32_f16(fk0, fql[g][0], al, 0, 0, 0);
        al = __builtin_amdgcn_mfma_f32_16x16x32_f16(fk1, fql[g][1], al, 0, 0, 0);
        S0[g][mt] = ah + al;
      }
    }
    __builtin_amdgcn_s_setprio(0);

    // ---- softmax pass 0 (groups 0,1): defer-rescale, pack P, store ----
    {
      float tm[2];
#pragma unroll
      for (int g = 0; g < 2; ++g) {
        float t = -INFINITY;
#pragma unroll
        for (int mt = 0; mt < 4; ++mt)
#pragma unroll
          for (int j = 0; j < 4; ++j) t = fmaxf(t, S0[g][mt][j]);
        t = fmaxf(t, __shfl_xor(t, 16, 64));
        t = fmaxf(t, __shfl_xor(t, 32, 64));
        tm[g] = t;
      }
      const unsigned long long need =
          __ballot(tm[0] > m_i[0] + kThr || tm[1] > m_i[1] + kThr);
      if (need) {
        float alpha[2];
#pragma unroll
        for (int g = 0; g < 2; ++g) {
          const float mn = fmaxf(m_i[g], tm[g]);
          alpha[g] = fast_exp2(m_i[g] - mn);
          m_i[g] = mn;
          l_i[g] *= alpha[g];
        }
#pragma unroll
        for (int g = 0; g < 2; ++g)
#pragma unroll
          for (int j = 0; j < 4; ++j) {
            const float a = __shfl(alpha[g], quad * 4 + j, 64);
#pragma unroll
            for (int nd = 0; nd < 4; ++nd) O[g][nd][j] *= a;
          }
      }
#pragma unroll
      for (int g = 0; g < 2; ++g) {
        float rs = 0.f;
#pragma unroll
        for (int mt = 0; mt < 4; ++mt) {
          H4 hp;
#pragma unroll
          for (int j = 0; j < 4; ++j) {
            float pj = fast_exp2(S0[g][mt][j] - m_i[g]);
            rs += pj;
            hp.h[j] = (_Float16)pj;
          }
          *(uint2*)&sP[w * 64 + g * 16 + r][mt * 16 + quad * 4] = hp.u2;
        }
        rs += __shfl_xor(rs, 16, 64);
        rs += __shfl_xor(rs, 32, 64);
        l_i[g] += rs;
      }
    }

    // ---- QK pass 1 (q-groups 2,3) — hides SM0's P-write latency ----
    floatx4 S1[2][4];
    __builtin_amdgcn_s_setprio(1);
#pragma unroll
    for (int mt = 0; mt < 4; ++mt) {
      half8 fk0 = *(const half8*)&sK[cur][mt * 16 + r][quad * 8];
      half8 fk1 = *(const half8*)&sK[cur][mt * 16 + r][32 + quad * 8];
#pragma unroll
      for (int g = 0; g < 2; ++g) {
        floatx4 ah = {0.f, 0.f, 0.f, 0.f}, al = {0.f, 0.f, 0.f, 0.f};
        ah = __builtin_amdgcn_mfma_f32_16x16x32_f16(fk0, fqh[2 + g][0], ah, 0, 0, 0);
        ah = __builtin_amdgcn_mfma_f32_16x16x32_f16(fk1, fqh[2 + g][1], ah, 0, 0, 0);
        al = __builtin_amdgcn_mfma_f32_16x16x32_f16(fk0, fql[2 + g][0], al, 0, 0, 0);
        al = __builtin_amdgcn_mfma_f32_16x16x32_f16(fk1, fql[2 + g][1], al, 0, 0, 0);
        S1[g][mt] = ah + al;
      }
    }
    __builtin_amdgcn_s_setprio(0);

    // ---- PV first half: O[0],O[1]; fv read once and kept live ----
    half8 fv[2][4];
    __builtin_amdgcn_s_setprio(1);
#pragma unroll
    for (int ks = 0; ks < 2; ++ks) {
      half8 fp0 = *(const half8*)&sP[w * 64 + 0 * 16 + r][ks * 32 + quad * 8];
      half8 fp1 = *(const half8*)&sP[w * 64 + 1 * 16 + r][ks * 32 + quad * 8];
#pragma unroll
      for (int nd = 0; nd < 4; ++nd) {
        fv[ks][nd] = *(const half8*)&sVt[cur][nd * 16 + r][ks * 32 + quad * 8];
        O[0][nd] = __builtin_amdgcn_mfma_f32_16x16x32_f16(fp0, fv[ks][nd], O[0][nd], 0, 0, 0);
        O[1][nd] = __builtin_amdgcn_mfma_f32_16x16x32_f16(fp1, fv[ks][nd], O[1][nd], 0, 0, 0);
      }
    }
    __builtin_amdgcn_s_setprio(0);

    // ---- softmax pass 1 (groups 2,3): VALU overlaps PV0's MFMA ----
    {
      float tm[2];
#pragma unroll
      for (int g = 0; g < 2; ++g) {
        float t = -INFINITY;
#pragma unroll
        for (int mt = 0; mt < 4; ++mt)
#pragma unroll
          for (int j = 0; j < 4; ++j) t = fmaxf(t, S1[g][mt][j]);
        t = fmaxf(t, __shfl_xor(t, 16, 64));
        t = fmaxf(t, __shfl_xor(t, 32, 64));
        tm[g] = t;
      }
      const unsigned long long need =
          __ballot(tm[0] > m_i[2] + kThr || tm[1] > m_i[3] + kThr);
      if (need) {
        float alpha[2];
#pragma unroll
        for (int g = 0; g < 2; ++g) {
          const float mn = fmaxf(m_i[2 + g], tm[g]);
          alpha[g] = fast_exp2(m_i[2 + g] - mn);
          m_i[2 + g] = mn;
          l_i[2 + g] *= alpha[g];
        }
#pragma unroll
        for (int g = 0; g < 2; ++g)
#pragma unroll
          for (int j = 0; j < 4; ++j) {
            const float a = __shfl(alpha[g], quad * 4 + j, 64);
#pragma unroll
            for (int nd = 0; nd < 4; ++nd) O[2 + g][nd][j] *= a;
          }
      }
#pragma unroll
      for (int g = 0; g < 2; ++g) {
        float rs = 0.f;
#pragma unroll
        for (int mt = 0; mt < 4; ++mt) {
          H4 hp;
#pragma unroll
          for (int j = 0; j < 4; ++j) {
            float pj = fast_exp2(S1[g][mt][j] - m_i[2 + g]);
            rs += pj;
            hp.h[j] = (_Float16)pj;
          }
          *(uint2*)&sP[w * 64 + (2 + g) * 16 + r][mt * 16 + quad * 4] = hp.u2;
        }
        rs += __shfl_xor(rs, 16, 64);
        rs += __shfl_xor(rs, 32, 64);
        l_i[2 + g] += rs;
      }
    }

    // ---- PV second half: O[2],O[3] reusing live fv ----
    __builtin_amdgcn_s_setprio(1);
#pragma unroll
    for (int ks = 0; ks < 2; ++ks) {
      half8 fp2 = *(const half8*)&sP[w * 64 + 2 * 16 + r][ks * 32 + quad * 8];
      half8 fp3 = *(const half8*)&sP[w * 64 + 3 * 16 + r][ks * 32 + quad * 8];
#pragma unroll
      for (int nd = 0; nd < 4; ++nd) {
        O[2][nd] = __builtin_amdgcn_mfma_f32_16x16x32_f16(fp2, fv[ks][nd], O[2][nd], 0, 0, 0);
        O[3][nd] = __builtin_amdgcn_mfma_f32_16x16x32_f16(fp3, fv[ks][nd], O[3][nd], 0, 0, 0);
      }
    }
    __builtin_amdgcn_s_setprio(0);
  }

  // ---- epilogue: out[qrow][dim] = O / l ----
#pragma unroll
  for (int mtq = 0; mtq < 4; ++mtq)
#pragma unroll
    for (int j = 0; j < 4; ++j) {
      const float lrow = __shfl(l_i[mtq], quad * 4 + j, 64);
      const float linv = fast_rcp(lrow);
      float* dst =
          ob + (size_t)(qbase + w * 64 + mtq * 16 + quad * 4 + j) * kD + r;
#pragma unroll
      for (int nd = 0; nd < 4; ++nd) dst[nd * 16] = O[mtq][nd][j] * linv;
    }
}

}  // namespace

extern "C" void kernel_launch(void* const* d_in, const int* in_sizes, int n_in,
                              void* d_out, int out_size, void* d_ws, size_t ws_size,
                              hipStream_t stream) {
  const float* q = (const float*)d_in[0];
  const float* k = (const float*)d_in[1];
  const float* v = (const float*)d_in[2];
  float* out = (float*)d_out;

  fa_mfma_kernel<<<dim3(512), 256, 0, stream>>>(q, k, v, out);
}

// Round 6
// 173.835 us; speedup vs baseline: 1.1353x; 1.1353x over previous
//
#include <hip/hip_runtime.h>
#include <math.h>

namespace {

typedef _Float16 half8 __attribute__((ext_vector_type(8)));
typedef float floatx4 __attribute__((ext_vector_type(4)));

constexpr int kS   = 1024;
constexpr int kD   = 64;
constexpr int kPad = 72;   // 144 B row stride: 16B-aligned, 2-way bank phase (free)
constexpr float kLog2e = 1.4426950408889634f;
constexpr float kThr   = 8.0f;  // defer-rescale threshold (log2 space): p <= 2^8

union H4 { _Float16 h[4]; uint2 u2; };

__device__ __forceinline__ float fast_exp2(float x) {
#if __has_builtin(__builtin_amdgcn_exp2f)
  return __builtin_amdgcn_exp2f(x);
#else
  return exp2f(x);
#endif
}

__device__ __forceinline__ float fast_rcp(float x) {
#if __has_builtin(__builtin_amdgcn_rcpf)
  return __builtin_amdgcn_rcpf(x);
#else
  return 1.0f / x;
#endif
}

// Round-5 schedule (dbuf K/V, 1 barrier/tile, QK0->SM0->QK1->PV0->SM1->PV1)
// with the spill fixed: no fv-live array (PV1 re-reads sVt) and hi/lo QK
// products merged into ONE accumulator chain (saves 64 adds/tile + 32 regs).
// Peak live ~215 < 256-reg budget of (256,2). Round-5's fv+S1 liveness peaked
// ~250 -> scratch spill (+12 MB WRITE_SIZE), dur 88->114 us.
__global__ __launch_bounds__(256, 2)
void fa_mfma_kernel(const float* __restrict__ qg, const float* __restrict__ kg,
                    const float* __restrict__ vg, float* __restrict__ og) {
  __shared__ __align__(16) _Float16 sK [2][64][kPad];  // K tiles [buf][key][d]
  __shared__ __align__(16) _Float16 sVt[2][64][kPad];  // V^T tiles [buf][d][key]
  __shared__ __align__(16) _Float16 sP [256][kPad];    // P [qrow(block)][key]

  const int tid  = threadIdx.x;
  const int lane = tid & 63;
  const int w    = __builtin_amdgcn_readfirstlane(tid >> 6);
  const int quad = lane >> 4;
  const int r    = lane & 15;

  // XCD swizzle for 512 blocks: batch b's 4 q-tile blocks -> same XCD (i%8).
  const int blk = blockIdx.x;
  const int b     = (blk & 7) + 8 * (blk >> 5);  // batch 0..127
  const int qbase = ((blk >> 3) & 3) * 256;      // q-tile 0..3 (256 rows each)

  const float* qb = qg + (size_t)b * kS * kD;
  const float* kb = kg + (size_t)b * kS * kD;
  const float* vb = vg + (size_t)b * kS * kD;
  float*       ob = og + (size_t)b * kS * kD;

  // ---- Q fragments direct from global: hi/lo f16 split, pre-scaled log2e ----
  half8 fqh[4][2], fql[4][2];  // [ntq][ks]
#pragma unroll
  for (int ntq = 0; ntq < 4; ++ntq)
#pragma unroll
    for (int ks = 0; ks < 2; ++ks) {
      const float* src =
          qb + (size_t)(qbase + w * 64 + ntq * 16 + r) * kD + ks * 32 + quad * 8;
      float4 a = ((const float4*)src)[0];
      float4 c = ((const float4*)src)[1];
      float f[8] = {a.x, a.y, a.z, a.w, c.x, c.y, c.z, c.w};
#pragma unroll
      for (int j = 0; j < 8; ++j) {
        float x = f[j] * kLog2e;
        _Float16 h = (_Float16)x;
        fqh[ntq][ks][j] = h;
        fql[ntq][ks][j] = (_Float16)(x - (float)h);
      }
    }

  float m_i[4] = {-INFINITY, -INFINITY, -INFINITY, -INFINITY};
  float l_i[4] = {0.f, 0.f, 0.f, 0.f};
  floatx4 O[4][4];
#pragma unroll
  for (int a = 0; a < 4; ++a)
#pragma unroll
    for (int c = 0; c < 4; ++c) O[a][c] = floatx4{0.f, 0.f, 0.f, 0.f};

  // K/V prefetch registers (one tile ahead of the LDS buffer being staged).
  const int krow = tid >> 2, kc0 = (tid & 3) * 16;   // K row-major copy
  const int vkey4 = (tid & 15) * 4;                  // V: 4 consecutive keys
  const int vd0   = (tid >> 4) * 4;                  //    x 4 dims sub-tile
  float4 kbuf[4], vbuf[4];

  auto load_kv = [&](int kt) {
    const float4* ksrc = (const float4*)(kb + (size_t)(kt * 64 + krow) * kD + kc0);
#pragma unroll
    for (int g = 0; g < 4; ++g) kbuf[g] = ksrc[g];
#pragma unroll
    for (int kk = 0; kk < 4; ++kk)
      vbuf[kk] = *(const float4*)(vb + (size_t)(kt * 64 + vkey4 + kk) * kD + vd0);
  };
  auto stage = [&](int bi) {
#pragma unroll
    for (int g = 0; g < 4; ++g) {
      float t[4] = {kbuf[g].x, kbuf[g].y, kbuf[g].z, kbuf[g].w};
      H4 hk;
#pragma unroll
      for (int j = 0; j < 4; ++j) hk.h[j] = (_Float16)t[j];
      *(uint2*)&sK[bi][krow][kc0 + g * 4] = hk.u2;
    }
    float tv[4][4];
#pragma unroll
    for (int kk = 0; kk < 4; ++kk) {
      tv[kk][0] = vbuf[kk].x; tv[kk][1] = vbuf[kk].y;
      tv[kk][2] = vbuf[kk].z; tv[kk][3] = vbuf[kk].w;
    }
#pragma unroll
    for (int j = 0; j < 4; ++j) {
      H4 hv;
#pragma unroll
      for (int kk = 0; kk < 4; ++kk) hv.h[kk] = (_Float16)tv[kk][j];
      *(uint2*)&sVt[bi][vd0 + j][vkey4] = hv.u2;
    }
  };

  // Prologue: buf[0] <- tile 0; regs <- tile 1.
  load_kv(0);
  stage(0);
  load_kv(1);

  for (int kt = 0; kt < kS / 64; ++kt) {
    const int cur = kt & 1, nxt = cur ^ 1;
    __syncthreads();  // buf[cur] staged & prior reads of buf[nxt] done
    stage(nxt);                // tile kt+1 -> other buffer (overlaps compute)
    load_kv((kt + 2) & 15);    // regs <- tile kt+2 (wrap harmless)

    // ---- QK pass 0 (q-groups 0,1): hi+lo merged into one accumulator ----
    floatx4 S0[2][4];
    __builtin_amdgcn_s_setprio(1);
#pragma unroll
    for (int mt = 0; mt < 4; ++mt) {
      half8 fk0 = *(const half8*)&sK[cur][mt * 16 + r][quad * 8];
      half8 fk1 = *(const half8*)&sK[cur][mt * 16 + r][32 + quad * 8];
#pragma unroll
      for (int g = 0; g < 2; ++g) {
        floatx4 s = {0.f, 0.f, 0.f, 0.f};
        s = __builtin_amdgcn_mfma_f32_16x16x32_f16(fk0, fqh[g][0], s, 0, 0, 0);
        s = __builtin_amdgcn_mfma_f32_16x16x32_f16(fk1, fqh[g][1], s, 0, 0, 0);
        s = __builtin_amdgcn_mfma_f32_16x16x32_f16(fk0, fql[g][0], s, 0, 0, 0);
        s = __builtin_amdgcn_mfma_f32_16x16x32_f16(fk1, fql[g][1], s, 0, 0, 0);
        S0[g][mt] = s;
      }
    }
    __builtin_amdgcn_s_setprio(0);

    // ---- softmax pass 0 (groups 0,1): defer-rescale, pack P, store ----
    {
      float tm[2];
#pragma unroll
      for (int g = 0; g < 2; ++g) {
        float t = -INFINITY;
#pragma unroll
        for (int mt = 0; mt < 4; ++mt)
#pragma unroll
          for (int j = 0; j < 4; ++j) t = fmaxf(t, S0[g][mt][j]);
        t = fmaxf(t, __shfl_xor(t, 16, 64));
        t = fmaxf(t, __shfl_xor(t, 32, 64));
        tm[g] = t;
      }
      const unsigned long long need =
          __ballot(tm[0] > m_i[0] + kThr || tm[1] > m_i[1] + kThr);
      if (need) {
        float alpha[2];
#pragma unroll
        for (int g = 0; g < 2; ++g) {
          const float mn = fmaxf(m_i[g], tm[g]);
          alpha[g] = fast_exp2(m_i[g] - mn);
          m_i[g] = mn;
          l_i[g] *= alpha[g];
        }
#pragma unroll
        for (int g = 0; g < 2; ++g)
#pragma unroll
          for (int j = 0; j < 4; ++j) {
            const float a = __shfl(alpha[g], quad * 4 + j, 64);
#pragma unroll
            for (int nd = 0; nd < 4; ++nd) O[g][nd][j] *= a;
          }
      }
#pragma unroll
      for (int g = 0; g < 2; ++g) {
        float rs = 0.f;
#pragma unroll
        for (int mt = 0; mt < 4; ++mt) {
          H4 hp;
#pragma unroll
          for (int j = 0; j < 4; ++j) {
            float pj = fast_exp2(S0[g][mt][j] - m_i[g]);
            rs += pj;
            hp.h[j] = (_Float16)pj;
          }
          *(uint2*)&sP[w * 64 + g * 16 + r][mt * 16 + quad * 4] = hp.u2;
        }
        rs += __shfl_xor(rs, 16, 64);
        rs += __shfl_xor(rs, 32, 64);
        l_i[g] += rs;
      }
    }

    // ---- QK pass 1 (q-groups 2,3) — hides SM0's P-write latency ----
    floatx4 S1[2][4];
    __builtin_amdgcn_s_setprio(1);
#pragma unroll
    for (int mt = 0; mt < 4; ++mt) {
      half8 fk0 = *(const half8*)&sK[cur][mt * 16 + r][quad * 8];
      half8 fk1 = *(const half8*)&sK[cur][mt * 16 + r][32 + quad * 8];
#pragma unroll
      for (int g = 0; g < 2; ++g) {
        floatx4 s = {0.f, 0.f, 0.f, 0.f};
        s = __builtin_amdgcn_mfma_f32_16x16x32_f16(fk0, fqh[2 + g][0], s, 0, 0, 0);
        s = __builtin_amdgcn_mfma_f32_16x16x32_f16(fk1, fqh[2 + g][1], s, 0, 0, 0);
        s = __builtin_amdgcn_mfma_f32_16x16x32_f16(fk0, fql[2 + g][0], s, 0, 0, 0);
        s = __builtin_amdgcn_mfma_f32_16x16x32_f16(fk1, fql[2 + g][1], s, 0, 0, 0);
        S1[g][mt] = s;
      }
    }
    __builtin_amdgcn_s_setprio(0);

    // ---- PV first half: O[0],O[1] ----
    __builtin_amdgcn_s_setprio(1);
#pragma unroll
    for (int ks = 0; ks < 2; ++ks) {
      half8 fp0 = *(const half8*)&sP[w * 64 + 0 * 16 + r][ks * 32 + quad * 8];
      half8 fp1 = *(const half8*)&sP[w * 64 + 1 * 16 + r][ks * 32 + quad * 8];
#pragma unroll
      for (int nd = 0; nd < 4; ++nd) {
        half8 fv = *(const half8*)&sVt[cur][nd * 16 + r][ks * 32 + quad * 8];
        O[0][nd] = __builtin_amdgcn_mfma_f32_16x16x32_f16(fp0, fv, O[0][nd], 0, 0, 0);
        O[1][nd] = __builtin_amdgcn_mfma_f32_16x16x32_f16(fp1, fv, O[1][nd], 0, 0, 0);
      }
    }
    __builtin_amdgcn_s_setprio(0);

    // ---- softmax pass 1 (groups 2,3): VALU overlaps PV0's MFMA ----
    {
      float tm[2];
#pragma unroll
      for (int g = 0; g < 2; ++g) {
        float t = -INFINITY;
#pragma unroll
        for (int mt = 0; mt < 4; ++mt)
#pragma unroll
          for (int j = 0; j < 4; ++j) t = fmaxf(t, S1[g][mt][j]);
        t = fmaxf(t, __shfl_xor(t, 16, 64));
        t = fmaxf(t, __shfl_xor(t, 32, 64));
        tm[g] = t;
      }
      const unsigned long long need =
          __ballot(tm[0] > m_i[2] + kThr || tm[1] > m_i[3] + kThr);
      if (need) {
        float alpha[2];
#pragma unroll
        for (int g = 0; g < 2; ++g) {
          const float mn = fmaxf(m_i[2 + g], tm[g]);
          alpha[g] = fast_exp2(m_i[2 + g] - mn);
          m_i[2 + g] = mn;
          l_i[2 + g] *= alpha[g];
        }
#pragma unroll
        for (int g = 0; g < 2; ++g)
#pragma unroll
          for (int j = 0; j < 4; ++j) {
            const float a = __shfl(alpha[g], quad * 4 + j, 64);
#pragma unroll
            for (int nd = 0; nd < 4; ++nd) O[2 + g][nd][j] *= a;
          }
      }
#pragma unroll
      for (int g = 0; g < 2; ++g) {
        float rs = 0.f;
#pragma unroll
        for (int mt = 0; mt < 4; ++mt) {
          H4 hp;
#pragma unroll
          for (int j = 0; j < 4; ++j) {
            float pj = fast_exp2(S1[g][mt][j] - m_i[2 + g]);
            rs += pj;
            hp.h[j] = (_Float16)pj;
          }
          *(uint2*)&sP[w * 64 + (2 + g) * 16 + r][mt * 16 + quad * 4] = hp.u2;
        }
        rs += __shfl_xor(rs, 16, 64);
        rs += __shfl_xor(rs, 32, 64);
        l_i[2 + g] += rs;
      }
    }

    // ---- PV second half: O[2],O[3] (fv re-read from LDS; no long liveness) ----
    __builtin_amdgcn_s_setprio(1);
#pragma unroll
    for (int ks = 0; ks < 2; ++ks) {
      half8 fp2 = *(const half8*)&sP[w * 64 + 2 * 16 + r][ks * 32 + quad * 8];
      half8 fp3 = *(const half8*)&sP[w * 64 + 3 * 16 + r][ks * 32 + quad * 8];
#pragma unroll
      for (int nd = 0; nd < 4; ++nd) {
        half8 fv = *(const half8*)&sVt[cur][nd * 16 + r][ks * 32 + quad * 8];
        O[2][nd] = __builtin_amdgcn_mfma_f32_16x16x32_f16(fp2, fv, O[2][nd], 0, 0, 0);
        O[3][nd] = __builtin_amdgcn_mfma_f32_16x16x32_f16(fp3, fv, O[3][nd], 0, 0, 0);
      }
    }
    __builtin_amdgcn_s_setprio(0);
  }

  // ---- epilogue: out[qrow][dim] = O / l ----
#pragma unroll
  for (int mtq = 0; mtq < 4; ++mtq)
#pragma unroll
    for (int j = 0; j < 4; ++j) {
      const float lrow = __shfl(l_i[mtq], quad * 4 + j, 64);
      const float linv = fast_rcp(lrow);
      float* dst =
          ob + (size_t)(qbase + w * 64 + mtq * 16 + quad * 4 + j) * kD + r;
#pragma unroll
      for (int nd = 0; nd < 4; ++nd) dst[nd * 16] = O[mtq][nd][j] * linv;
    }
}

}  // namespace

extern "C" void kernel_launch(void* const* d_in, const int* in_sizes, int n_in,
                              void* d_out, int out_size, void* d_ws, size_t ws_size,
                              hipStream_t stream) {
  const float* q = (const float*)d_in[0];
  const float* k = (const float*)d_in[1];
  const float* v = (const float*)d_in[2];
  float* out = (float*)d_out;

  fa_mfma_kernel<<<dim3(512), 256, 0, stream>>>(q, k, v, out);
}